// Round 3
// baseline (150.175 us; speedup 1.0000x reference)
//
#include <hip/hip_runtime.h>

#define NUM_USER   4096
#define NUM_ITEM   16384
#define NUM_HIDDEN 64
#define B_SZ       1024
#define L_SZ       50
#define KROWS      64    // max batch rows tracked per user (P(overflow) ~ 0 for 1024 draws into 4096 bins)
#define NBUCKET    1024  // spread the unique-pair count across buckets to kill atomic contention
#define SEG_ITEMS  1024  // items per block (256 threads x 4 floats)
#define SEGS_PER_USER (NUM_ITEM / SEG_ITEMS)  // 16

// Bucket batch rows by user id so the fill kernel can find all rows sharing its user.
__global__ void build_rows_kernel(const int* __restrict__ idx_user,
                                  int* __restrict__ user_count,
                                  int* __restrict__ user_rows) {
    int b = blockIdx.x * blockDim.x + threadIdx.x;
    if (b < B_SZ) {
        int u = idx_user[b];
        int slot = atomicAdd(&user_count[u], 1);
        if (slot < KROWS) user_rows[u * KROWS + slot] = b;
    }
}

// Fused zero-fill + scatter: each block owns (user u, item segment of 1024) in BOTH
// output planes and writes every element exactly once. Users absent from the batch
// (~78%) take the pure float4 zero-store fast path. For present users, each wave
// scans the user's pairs (wave-uniform loop); a pair whose item lands in the wave's
// 256-item window triggers a cooperative 64-lane dot product. Label duplicates are
// resolved by max sequence number b*L+l == numpy C-order last-write-wins, which is
// processing-order independent -> deterministic across replays.
__global__ void fused_fill_kernel(const int* __restrict__ item_sets,
                                  const float* __restrict__ rating_sets,
                                  const float* __restrict__ embed_user,
                                  const float* __restrict__ embed_item,
                                  const int* __restrict__ user_count,
                                  const int* __restrict__ user_rows,
                                  float* __restrict__ pred_mask,
                                  float* __restrict__ label,
                                  unsigned int* __restrict__ ucount) {
    const int unit = blockIdx.x;                  // 0 .. NUM_USER*SEGS_PER_USER-1
    const int u    = unit >> 4;                   // SEGS_PER_USER == 16
    const int seg  = unit & (SEGS_PER_USER - 1);
    const int t    = threadIdx.x;                 // 0..255
    const int lane = t & 63;
    const int jt   = seg * SEG_ITEMS + t * 4;     // first of this thread's 4 items

    float4 pv = {0.f, 0.f, 0.f, 0.f};
    float4 lv = {0.f, 0.f, 0.f, 0.f};
    int bs0 = -1, bs1 = -1, bs2 = -1, bs3 = -1;   // best (max) seq per owned element

    int r = user_count[u];
    if (r > KROWS) r = KROWS;

    if (r > 0) {
        const int   wj0 = seg * SEG_ITEMS + (t >> 6) * 256;  // wave's 256-item window
        const float eu  = embed_user[u * NUM_HIDDEN + lane];
        for (int s = 0; s < r; ++s) {
            const int b       = user_rows[u * KROWS + s];
            const int rowbase = b * L_SZ;
            for (int l = 0; l < L_SZ; ++l) {
                const int it = item_sets[rowbase + l];        // wave-uniform
                if ((unsigned)(it - wj0) < 256u) {            // uniform branch
                    // cooperative 64-wide dot product, all lanes get v
                    float v = eu * embed_item[it * NUM_HIDDEN + lane];
                    #pragma unroll
                    for (int m = 32; m >= 1; m >>= 1) v += __shfl_xor(v, m, 64);
                    const int rel = it - jt;                  // 0..3 iff this thread owns it
                    if ((unsigned)rel < 4u) {
                        const int seq = rowbase + l;
                        const float rating = rating_sets[rowbase + l];
                        if (rel == 0)      { pv.x = v; if (seq > bs0) { bs0 = seq; lv.x = rating; } }
                        else if (rel == 1) { pv.y = v; if (seq > bs1) { bs1 = seq; lv.y = rating; } }
                        else if (rel == 2) { pv.z = v; if (seq > bs2) { bs2 = seq; lv.z = rating; } }
                        else               { pv.w = v; if (seq > bs3) { bs3 = seq; lv.w = rating; } }
                    }
                }
            }
        }
        // count unique nonzero cells this thread owns (== contribution to sum(mask))
        unsigned int n = (bs0 >= 0) + (bs1 >= 0) + (bs2 >= 0) + (bs3 >= 0);
        #pragma unroll
        for (int m = 32; m >= 1; m >>= 1) n += __shfl_xor(n, m, 64);
        if (lane == 0 && n > 0)
            atomicAdd(&ucount[unit & (NBUCKET - 1)], n);
    }

    const size_t cell = (size_t)u * NUM_ITEM + jt;
    *(float4*)(pred_mask + cell) = pv;
    *(float4*)(label     + cell) = lv;
}

// One block: reduce the NBUCKET partial counts, emit sparsity scalar.
__global__ void sparsity_kernel(const unsigned int* __restrict__ ucount,
                                float* __restrict__ out) {
    __shared__ unsigned int warp_sum[4];
    const int t = threadIdx.x;            // 256 threads = 4 waves
    unsigned int s = 0;
    #pragma unroll
    for (int i = 0; i < NBUCKET / 256; ++i) s += ucount[t + i * 256];
    #pragma unroll
    for (int m = 32; m >= 1; m >>= 1) s += __shfl_xor(s, m, 64);
    if ((t & 63) == 0) warp_sum[t >> 6] = s;
    __syncthreads();
    if (t == 0) {
        unsigned int total = warp_sum[0] + warp_sum[1] + warp_sum[2] + warp_sum[3];
        out[0] = (float)((double)NUM_USER * (double)NUM_ITEM / (double)total);
    }
}

extern "C" void kernel_launch(void* const* d_in, const int* in_sizes, int n_in,
                              void* d_out, int out_size, void* d_ws, size_t ws_size,
                              hipStream_t stream) {
    const int*   idx_user    = (const int*)d_in[0];
    const int*   item_sets   = (const int*)d_in[1];
    const float* rating_sets = (const float*)d_in[2];
    const float* embed_user  = (const float*)d_in[3];
    const float* embed_item  = (const float*)d_in[4];

    float* pred_mask = (float*)d_out;
    float* label     = pred_mask + (size_t)NUM_USER * NUM_ITEM;
    float* sparsity  = label     + (size_t)NUM_USER * NUM_ITEM;

    // ws layout: [user_count: 4096][ucount: NBUCKET][user_rows: 4096*KROWS]
    int*          user_count = (int*)d_ws;
    unsigned int* ucount     = (unsigned int*)(user_count + NUM_USER);
    int*          user_rows  = (int*)(ucount + NBUCKET);

    // Zero only the counters (20 KB). user_rows is fully rebuilt via the counts;
    // every d_out element is written by fused_fill/sparsity, so no output memset.
    hipMemsetAsync(d_ws, 0, (size_t)(NUM_USER + NBUCKET) * sizeof(int), stream);

    build_rows_kernel<<<(B_SZ + 255) / 256, 256, 0, stream>>>(idx_user, user_count, user_rows);
    fused_fill_kernel<<<NUM_USER * SEGS_PER_USER, 256, 0, stream>>>(
        item_sets, rating_sets, embed_user, embed_item,
        user_count, user_rows, pred_mask, label, ucount);
    sparsity_kernel<<<1, 256, 0, stream>>>(ucount, sparsity);
}

// Round 4
// 142.463 us; speedup vs baseline: 1.0541x; 1.0541x over previous
//
#include <hip/hip_runtime.h>

#define NUM_USER   4096
#define NUM_ITEM   16384
#define NUM_HIDDEN 64
#define B_SZ       1024
#define L_SZ       50
#define NPAIR      (B_SZ * L_SZ)          // 51200
#define SEG_ITEMS  1024                   // items per segment (256 threads x 4 floats)
#define NSEG       (NUM_USER * (NUM_ITEM / SEG_ITEMS))  // 65536 segments tile the output
#define CAP        64                     // max binned pairs per segment (realistic max ~30)
#define NBUCKET    1024                   // bucketed unique-cell counters (atomic spread)

// One wave per (b,l) pair: cooperative 64-lane dot product, then append
// (key, v, rating) to the owning segment's bin. key = (seq<<10) | item_low,
// seq = b*L+l == numpy C-order; max-key wins later -> order independent.
__global__ void pair_kernel(const int* __restrict__ idx_user,
                            const int* __restrict__ item_sets,
                            const float* __restrict__ rating_sets,
                            const float* __restrict__ embed_user,
                            const float* __restrict__ embed_item,
                            unsigned int* __restrict__ seg_count,
                            unsigned int* __restrict__ seg_key,
                            float* __restrict__ seg_val,
                            float* __restrict__ seg_rat) {
    const int p    = blockIdx.x * 4 + (threadIdx.x >> 6);   // 4 waves/block
    const int lane = threadIdx.x & 63;
    if (p >= NPAIR) return;
    const int b  = p / L_SZ;
    const int u  = idx_user[b];
    const int it = item_sets[p];

    float v = embed_user[u * NUM_HIDDEN + lane] * embed_item[it * NUM_HIDDEN + lane];
    #pragma unroll
    for (int m = 32; m >= 1; m >>= 1) v += __shfl_xor(v, m, 64);

    if (lane == 0) {
        const int seg = u * (NUM_ITEM / SEG_ITEMS) + (it >> 10);
        unsigned int slot = atomicAdd(&seg_count[seg], 1u);
        if (slot < CAP) {
            const int base = seg * CAP + (int)slot;
            seg_key[base] = ((unsigned int)p << 10) | (unsigned int)(it & (SEG_ITEMS - 1));
            seg_val[base] = v;
            seg_rat[base] = rating_sets[p];
        }
    }
}

// Each block owns one 1024-item segment of BOTH output planes and writes every
// element exactly once. Empty segment (the common case) -> pure float4 zero
// store. Non-empty -> scan the k (~4) binned entries, resolve last-write-wins
// via max key, and count matched (unique) cells for the sparsity scalar.
__global__ void fill_inject_kernel(const unsigned int* __restrict__ seg_count,
                                   const unsigned int* __restrict__ seg_key,
                                   const float* __restrict__ seg_val,
                                   const float* __restrict__ seg_rat,
                                   float* __restrict__ pred_mask,
                                   float* __restrict__ label,
                                   unsigned int* __restrict__ ucount) {
    const int seg = blockIdx.x;
    const int t   = threadIdx.x;                   // 0..255, owns items t*4..t*4+3
    const size_t cell = (size_t)seg * SEG_ITEMS + t * 4;

    float4 pv = {0.f, 0.f, 0.f, 0.f};
    float4 lv = {0.f, 0.f, 0.f, 0.f};

    unsigned int k = seg_count[seg];
    if (k > CAP) k = CAP;

    if (k > 0) {
        int bk0 = -1, bk1 = -1, bk2 = -1, bk3 = -1;    // best key per owned item
        int bi0 = 0,  bi1 = 0,  bi2 = 0,  bi3 = 0;     // its entry index
        const int base = seg * CAP;
        const int j0   = t * 4;
        for (int i = 0; i < (int)k; ++i) {
            const int key  = (int)seg_key[base + i];   // < 2^26, sign-safe
            const int rel  = (key & (SEG_ITEMS - 1)) - j0;
            // static-index selection (no runtime-indexed arrays -> stays in VGPRs)
            bool m0 = (rel == 0) && (key > bk0); bk0 = m0 ? key : bk0; bi0 = m0 ? i : bi0;
            bool m1 = (rel == 1) && (key > bk1); bk1 = m1 ? key : bk1; bi1 = m1 ? i : bi1;
            bool m2 = (rel == 2) && (key > bk2); bk2 = m2 ? key : bk2; bi2 = m2 ? i : bi2;
            bool m3 = (rel == 3) && (key > bk3); bk3 = m3 ? key : bk3; bi3 = m3 ? i : bi3;
        }
        if (bk0 >= 0) { pv.x = seg_val[base + bi0]; lv.x = seg_rat[base + bi0]; }
        if (bk1 >= 0) { pv.y = seg_val[base + bi1]; lv.y = seg_rat[base + bi1]; }
        if (bk2 >= 0) { pv.z = seg_val[base + bi2]; lv.z = seg_rat[base + bi2]; }
        if (bk3 >= 0) { pv.w = seg_val[base + bi3]; lv.w = seg_rat[base + bi3]; }

        // unique-cell count for sparsity (duplicates collapse by construction)
        unsigned int n = (bk0 >= 0) + (bk1 >= 0) + (bk2 >= 0) + (bk3 >= 0);
        #pragma unroll
        for (int m = 32; m >= 1; m >>= 1) n += __shfl_xor(n, m, 64);
        if ((t & 63) == 0 && n > 0)
            atomicAdd(&ucount[seg & (NBUCKET - 1)], n);
    }

    *(float4*)(pred_mask + cell) = pv;
    *(float4*)(label     + cell) = lv;
}

// One block: reduce the NBUCKET partial counts, emit sparsity scalar.
__global__ void sparsity_kernel(const unsigned int* __restrict__ ucount,
                                float* __restrict__ out) {
    __shared__ unsigned int warp_sum[4];
    const int t = threadIdx.x;            // 256 threads = 4 waves
    unsigned int s = 0;
    #pragma unroll
    for (int i = 0; i < NBUCKET / 256; ++i) s += ucount[t + i * 256];
    #pragma unroll
    for (int m = 32; m >= 1; m >>= 1) s += __shfl_xor(s, m, 64);
    if ((t & 63) == 0) warp_sum[t >> 6] = s;
    __syncthreads();
    if (t == 0) {
        unsigned int total = warp_sum[0] + warp_sum[1] + warp_sum[2] + warp_sum[3];
        out[0] = (float)((double)NUM_USER * (double)NUM_ITEM / (double)total);
    }
}

extern "C" void kernel_launch(void* const* d_in, const int* in_sizes, int n_in,
                              void* d_out, int out_size, void* d_ws, size_t ws_size,
                              hipStream_t stream) {
    const int*   idx_user    = (const int*)d_in[0];
    const int*   item_sets   = (const int*)d_in[1];
    const float* rating_sets = (const float*)d_in[2];
    const float* embed_user  = (const float*)d_in[3];
    const float* embed_item  = (const float*)d_in[4];

    float* pred_mask = (float*)d_out;
    float* label     = pred_mask + (size_t)NUM_USER * NUM_ITEM;
    float* sparsity  = label     + (size_t)NUM_USER * NUM_ITEM;

    // ws layout: [seg_count: NSEG u32][ucount: NBUCKET u32][key|val|rat: NSEG*CAP each]
    unsigned int* seg_count = (unsigned int*)d_ws;
    unsigned int* ucount    = seg_count + NSEG;
    unsigned int* seg_key   = ucount + NBUCKET;
    float*        seg_val   = (float*)(seg_key + (size_t)NSEG * CAP);
    float*        seg_rat   = seg_val + (size_t)NSEG * CAP;

    // Zero only the counters (260 KB); bin payloads are fully rewritten each call
    // (slots 0..count-1 are always freshly stored before being read).
    hipMemsetAsync(d_ws, 0, (size_t)(NSEG + NBUCKET) * sizeof(int), stream);

    pair_kernel<<<NPAIR / 4, 256, 0, stream>>>(idx_user, item_sets, rating_sets,
                                               embed_user, embed_item,
                                               seg_count, seg_key, seg_val, seg_rat);
    fill_inject_kernel<<<NSEG, 256, 0, stream>>>(seg_count, seg_key, seg_val, seg_rat,
                                                 pred_mask, label, ucount);
    sparsity_kernel<<<1, 256, 0, stream>>>(ucount, sparsity);
}

// Round 5
// 139.235 us; speedup vs baseline: 1.0786x; 1.0232x over previous
//
#include <hip/hip_runtime.h>

#define NUM_USER   4096
#define NUM_ITEM   16384
#define NUM_HIDDEN 64
#define B_SZ       1024
#define L_SZ       50
#define NPAIR      (B_SZ * L_SZ)   // 51200
#define KROWS      64              // max batch rows tracked per user
#define NBUCKET    1024            // bucketed unique-cell counters (atomic spread)
#define FILL_BLOCKS 2048           // 8 blocks/CU; each owns a contiguous 256 KB chunk

// Memset-shaped zero fill: no loads, no branches, fat blocks. Covers both
// pred_mask and label planes (2^29 bytes) in one launch.
__global__ void zero_fill_kernel(float4* __restrict__ out) {
    const size_t base = (size_t)blockIdx.x * (256u * 64u) + threadIdx.x;
    const float4 z = {0.f, 0.f, 0.f, 0.f};
    #pragma unroll 8
    for (int i = 0; i < 64; ++i)
        out[base + (size_t)i * 256] = z;
}

// Bucket batch rows by user id so the scatter kernel can find all rows sharing its user.
__global__ void build_rows_kernel(const int* __restrict__ idx_user,
                                  int* __restrict__ user_count,
                                  int* __restrict__ user_rows) {
    int b = blockIdx.x * blockDim.x + threadIdx.x;
    if (b < B_SZ) {
        int u = idx_user[b];
        int slot = atomicAdd(&user_count[u], 1);
        if (slot < KROWS) user_rows[u * KROWS + slot] = b;
    }
}

// One wave per (b,l) pair, 4 waves/block: lane h holds hidden-dim h of the dot.
// Lanes 0..49 check duplicate (u,item) pairs with LATER sequence number in
// parallel; ballot decides whether this pair is the numpy last-write winner.
// Winner selection is order-independent -> deterministic across graph replays.
__global__ void scatter_kernel(const int* __restrict__ idx_user,
                               const int* __restrict__ item_sets,
                               const float* __restrict__ rating_sets,
                               const float* __restrict__ embed_user,
                               const float* __restrict__ embed_item,
                               float* __restrict__ pred_mask,
                               float* __restrict__ label,
                               const int* __restrict__ user_count,
                               const int* __restrict__ user_rows,
                               unsigned int* __restrict__ ucount) {
    const int p    = blockIdx.x * 4 + (threadIdx.x >> 6);   // pair idx, seq order == numpy C-order
    const int lane = threadIdx.x & 63;
    const int b    = p / L_SZ;
    const int l    = p - b * L_SZ;

    const int u  = idx_user[b];
    const int it = item_sets[p];

    // 64-wide dot product: lane h multiplies element h, butterfly reduce across the wave.
    float v = embed_user[u * NUM_HIDDEN + lane] * embed_item[it * NUM_HIDDEN + lane];
    #pragma unroll
    for (int m = 32; m >= 1; m >>= 1) v += __shfl_xor(v, m, 64);

    // Duplicate detection: any pair with larger seq (same row later l, or later row
    // of the same user) targeting the same item? Lanes 0..49 each check one slot.
    bool dup = false;
    if (lane > l && lane < L_SZ) dup = (item_sets[b * L_SZ + lane] == it);
    int cnt = user_count[u];
    if (cnt > KROWS) cnt = KROWS;
    for (int s = 0; s < cnt; ++s) {
        int b2 = user_rows[u * KROWS + s];
        if (b2 > b && lane < L_SZ) dup |= (item_sets[b2 * L_SZ + lane] == it);
    }
    unsigned long long anydup = __ballot(dup);

    if (lane == 0) {
        size_t cell = (size_t)u * NUM_ITEM + it;
        // pred value identical for all duplicates of (u,it) -> unconditional store safe.
        pred_mask[cell] = v;
        if (anydup == 0ull) {
            label[cell] = rating_sets[p];                    // last writer in numpy order
            atomicAdd(&ucount[p & (NBUCKET - 1)], 1u);       // ~50 atomics/bucket, no contention
        }
    }
}

// One block: reduce the NBUCKET partial counts, emit sparsity scalar.
__global__ void sparsity_kernel(const unsigned int* __restrict__ ucount,
                                float* __restrict__ out) {
    __shared__ unsigned int warp_sum[4];
    const int t = threadIdx.x;            // 256 threads = 4 waves
    unsigned int s = 0;
    #pragma unroll
    for (int i = 0; i < NBUCKET / 256; ++i) s += ucount[t + i * 256];
    #pragma unroll
    for (int m = 32; m >= 1; m >>= 1) s += __shfl_xor(s, m, 64);
    if ((t & 63) == 0) warp_sum[t >> 6] = s;
    __syncthreads();
    if (t == 0) {
        unsigned int total = warp_sum[0] + warp_sum[1] + warp_sum[2] + warp_sum[3];
        out[0] = (float)((double)NUM_USER * (double)NUM_ITEM / (double)total);
    }
}

extern "C" void kernel_launch(void* const* d_in, const int* in_sizes, int n_in,
                              void* d_out, int out_size, void* d_ws, size_t ws_size,
                              hipStream_t stream) {
    const int*   idx_user    = (const int*)d_in[0];
    const int*   item_sets   = (const int*)d_in[1];
    const float* rating_sets = (const float*)d_in[2];
    const float* embed_user  = (const float*)d_in[3];
    const float* embed_item  = (const float*)d_in[4];

    float* pred_mask = (float*)d_out;
    float* label     = pred_mask + (size_t)NUM_USER * NUM_ITEM;
    float* sparsity  = label     + (size_t)NUM_USER * NUM_ITEM;

    // ws layout: [user_count: 4096][ucount: NBUCKET][user_rows: 4096*KROWS]
    int*          user_count = (int*)d_ws;
    unsigned int* ucount     = (unsigned int*)(user_count + NUM_USER);
    int*          user_rows  = (int*)(ucount + NBUCKET);

    // Zero only the counters (20 KB); user_rows slots 0..count-1 are always
    // freshly stored before being read.
    hipMemsetAsync(d_ws, 0, (size_t)(NUM_USER + NBUCKET) * sizeof(int), stream);

    build_rows_kernel<<<(B_SZ + 255) / 256, 256, 0, stream>>>(idx_user, user_count, user_rows);
    zero_fill_kernel<<<FILL_BLOCKS, 256, 0, stream>>>((float4*)d_out);   // both planes
    scatter_kernel<<<NPAIR / 4, 256, 0, stream>>>(idx_user, item_sets, rating_sets,
                                                  embed_user, embed_item,
                                                  pred_mask, label,
                                                  user_count, user_rows, ucount);
    sparsity_kernel<<<1, 256, 0, stream>>>(ucount, sparsity);
}